// Round 7
// baseline (966.911 us; speedup 1.0000x reference)
//
#include <hip/hip_runtime.h>
#include <hip/hip_bf16.h>

#define F 128
#define MGCS 60
#define NWIN 800
#define RFS 512
#define NBLK 4
#define NLAY 9
#define SQF 0.70710678118f

typedef __attribute__((ext_vector_type(8))) short s16x8;
typedef __attribute__((ext_vector_type(4))) float f32x4;

#define VMCNT(n) asm volatile("s_waitcnt vmcnt(" #n ")" ::: "memory")

// combined tanh(o0)*sigmoid(o1) + o2, 2 exp + 1 rcp.
__device__ __forceinline__ float gated_act(float o0, float o1, float o2) {
  o0 = fminf(fmaxf(o0, -21.f), 21.f);
  o1 = fminf(fmaxf(o1, -21.f), 21.f);
  float a = __expf(2.f * o0);
  float b = __expf(-o1);
  float r = (a - 1.f) * __builtin_amdgcn_rcpf((a + 1.f) * (1.f + b));
  return (r + o2) * SQF;
}

__device__ __forceinline__ float bf2f(short s) {
  union { unsigned u; float f; } t;
  t.u = ((unsigned)(unsigned short)s) << 16;
  return t.f;
}

// ---------------- precompute kernels ----------------

__global__ void k_cond(const float* __restrict__ mgc, const float* __restrict__ cond_w,
                       const float* __restrict__ cond_b, float* __restrict__ cond) {
  int i = blockIdx.x * blockDim.x + threadIdx.x;
  if (i >= NWIN * MGCS) return;
  int n = i / MGCS, m = i % MGCS;
  int t = n / 200, u = n % 200;
  const float* wrow = cond_w + (size_t)(u * MGCS + m) * MGCS;
  const float* mr = mgc + t * MGCS;
  float s = cond_b[u * MGCS + m];
#pragma unroll
  for (int k = 0; k < MGCS; ++k) s += mr[k] * wrow[k];
  cond[i] = tanhf(s);
}

// CI[w][n][f]: tiled GEMM. grid (72, 7); 256 threads; 128n x 128f tile per block.
__global__ __launch_bounds__(256) void k_ci(
    const float* __restrict__ cond, const float* __restrict__ clw,
    const float* __restrict__ clb, float* __restrict__ CI) {
  int w = blockIdx.x;
  int n0 = blockIdx.y * 128;
  __shared__ float wsh[128][61];
  __shared__ float csh[128][61];
  int tid = threadIdx.x;
  for (int idx = tid; idx < 128 * MGCS; idx += 256) {
    int f = idx / MGCS, k = idx % MGCS;
    wsh[f][k] = clw[((size_t)w * 128 + f) * MGCS + k];
  }
  for (int idx = tid; idx < 128 * MGCS; idx += 256) {
    int n = idx / MGCS, k = idx % MGCS;
    csh[n][k] = (n0 + n < NWIN) ? cond[(n0 + n) * MGCS + k] : 0.f;
  }
  __syncthreads();
  int tn = tid >> 4, tf = tid & 15;
  float acc[8][8] = {};
  for (int k = 0; k < MGCS; ++k) {
    float a[8], b[8];
#pragma unroll
    for (int i = 0; i < 8; ++i) a[i] = csh[i * 16 + tn][k];
#pragma unroll
    for (int j = 0; j < 8; ++j) b[j] = wsh[j * 16 + tf][k];
#pragma unroll
    for (int i = 0; i < 8; ++i)
#pragma unroll
      for (int j = 0; j < 8; ++j) acc[i][j] += a[i] * b[j];
  }
  float bb[8];
#pragma unroll
  for (int j = 0; j < 8; ++j) bb[j] = clb[w * 128 + j * 16 + tf];
#pragma unroll
  for (int i = 0; i < 8; ++i) {
    int n = n0 + i * 16 + tn;
    if (n < NWIN) {
#pragma unroll
      for (int j = 0; j < 8; ++j)
        CI[((size_t)w * NWIN + n) * 128 + j * 16 + tf] = acc[i][j] + bb[j];
    }
  }
}

// W2[wl][tf][k] (bf16) = convL_w[blk][lm][t][f][c][k2], tf = t*128+f, k = k2*128+c
__global__ void k_wt(const float* __restrict__ convL_w, __hip_bfloat16* __restrict__ W2) {
  int i = blockIdx.x * blockDim.x + threadIdx.x;
  const int total = NBLK * 8 * 384 * 256;
  if (i >= total) return;
  int k = i & 255;
  int tf = (i >> 8) % 384;
  int wl = i / (384 * 256);
  int t = tf >> 7, f = tf & 127;
  int k2 = k >> 7, c = k & 127;
  W2[i] = __float2bfloat16(convL_w[(((size_t)(wl * 3 + t) * 128 + f) * 128 + c) * 2 + k2]);
}

__global__ void k_outsig(const float* __restrict__ signal, float* __restrict__ out) {
  int i = blockIdx.x * blockDim.x + threadIdx.x;
  if (i < NWIN) out[i] = signal[RFS + i];
}

// ---------------- per-block kernels ----------------

// CV[s][tf] = b0[tf] + prev[s]*w0[tf][0] + prev[s+1]*w0[tf][1], s in [0,1310)
__global__ void k_pre0(const float* __restrict__ prev, const float* __restrict__ w0,
                       const float* __restrict__ b0, float* __restrict__ CV) {
  int i = blockIdx.x * blockDim.x + threadIdx.x;
  if (i >= 1310 * 384) return;
  int tf = i % 384, s = i / 384;
  CV[i] = b0[tf] + prev[s] * w0[tf * 2] + prev[s + 1] * w0[tf * 2 + 1];
}

// layer 0: out[n][j][f] = act(CV[n+2j][f..] + CI(n)), 8 f per thread.
__global__ void k_layer0(const float* __restrict__ CV, const float* __restrict__ CIb,
                         __hip_bfloat16* __restrict__ out) {
  int i = blockIdx.x * blockDim.x + threadIdx.x;
  if (i >= NWIN * 256 * 16) return;
  int fg = i & 15;
  int rest = i >> 4;
  int j = rest & 255;
  int n = rest >> 8;
  int f0 = fg * 8;
  const float* cv = CV + (size_t)(n + 2 * j) * 384;
  const float* ci = CIb + (size_t)n * F;
  float4 c0a = *(const float4*)(cv + f0),       c0b = *(const float4*)(cv + f0 + 4);
  float4 c1a = *(const float4*)(cv + 128 + f0), c1b = *(const float4*)(cv + 132 + f0);
  float4 c2a = *(const float4*)(cv + 256 + f0), c2b = *(const float4*)(cv + 260 + f0);
  float4 i0a = *(const float4*)(ci + f0),       i0b = *(const float4*)(ci + f0 + 4);
  float4 i1a = *(const float4*)(ci + (size_t)NWIN * F + f0);
  float4 i1b = *(const float4*)(ci + (size_t)NWIN * F + f0 + 4);
  s16x8 res;
#pragma unroll
  for (int e = 0; e < 8; ++e) {
    float o0 = ((e < 4) ? (&c0a.x)[e] : (&c0b.x)[e - 4]) + ((e < 4) ? (&i0a.x)[e] : (&i0b.x)[e - 4]);
    float o1 = ((e < 4) ? (&c1a.x)[e] : (&c1b.x)[e - 4]) + ((e < 4) ? (&i1a.x)[e] : (&i1b.x)[e - 4]);
    float o2 = (e < 4) ? (&c2a.x)[e] : (&c2b.x)[e - 4];
    __hip_bfloat16 h = __float2bfloat16(gated_act(o0, o1, o2));
    res[e] = *(short*)&h;
  }
  *(s16x8*)(out + ((size_t)(n * 256 + j)) * F + f0) = res;
}

// Weight-stationary persistent MFMA GEMM, 512 threads = 8 waves, each wave owns
// 16 of the 128 f-cols (3 gates in regs). A tiles (BM=64) stream through
// double-buffered LDS. Output staged into the DEAD compute buffer (first 16KB
// of AsB[cur]) so LDS stays at 64KB -> 2 blocks/CU.
#define BM 64
__global__ __launch_bounds__(512, 2) void k_gemm(
    const __hip_bfloat16* __restrict__ A, const __hip_bfloat16* __restrict__ W2,
    const float* __restrict__ bias, const float* __restrict__ CI0,
    const float* __restrict__ CI1, __hip_bfloat16* __restrict__ out,
    int M, int lgL) {
  __shared__ char AsB[2][BM * 512];               // 2 x 32 KB only
  const int tid = threadIdx.x;
  const int lane = tid & 63, wid = tid >> 6;
  const int ntiles = (M + BM - 1) / BM;
  const int gdx = gridDim.x;
  const int col = lane & 15, kg = lane >> 4;

  // ---- B into registers (once) ----
  const char* Wb = (const char*)W2;
  const int f = wid * 16 + col;
  s16x8 breg[3][8];
#pragma unroll
  for (int g = 0; g < 3; ++g)
#pragma unroll
    for (int ks = 0; ks < 8; ++ks)
      breg[g][ks] = *(const s16x8*)(Wb + (size_t)(g * 128 + f) * 512 + ks * 64 + kg * 16);
  const float bz0 = bias[f], bz1 = bias[128 + f], bz2 = bias[256 + f];

  const char* Ab = (const char*)A;
  const int half = lane >> 5;
  const int lin = (lane & 31) * 16;
  // ---- prologue: stage first tile into buf0 ----
#pragma unroll
  for (int it = 0; it < 4; ++it) {
    int inst = wid * 4 + it;
    int row = inst * 2 + half;
    const char* src = Ab + (size_t)blockIdx.x * (BM * 512) + row * 512 + (lin ^ ((row & 7) << 4));
    __builtin_amdgcn_global_load_lds(
        (const __attribute__((address_space(1))) unsigned int*)src,
        (__attribute__((address_space(3))) unsigned int*)(&AsB[0][0] + inst * 1024), 16, 0, 0);
  }

  int cur = 0;
  for (int t = blockIdx.x; t < ntiles; t += gdx) {
    int tn = t + gdx;
    if (tn < ntiles) {
      char* dst = &AsB[cur ^ 1][0];
#pragma unroll
      for (int it = 0; it < 4; ++it) {
        int inst = wid * 4 + it;
        int row = inst * 2 + half;
        const char* src = Ab + (size_t)tn * (BM * 512) + row * 512 + (lin ^ ((row & 7) << 4));
        __builtin_amdgcn_global_load_lds(
            (const __attribute__((address_space(1))) unsigned int*)src,
            (__attribute__((address_space(3))) unsigned int*)(dst + inst * 1024), 16, 0, 0);
      }
      VMCNT(4);            // current tile's loads done; next tile's stay in flight
    } else {
      VMCNT(0);
    }
    __builtin_amdgcn_s_barrier();
    __builtin_amdgcn_sched_barrier(0);

    f32x4 acc[4][3];
#pragma unroll
    for (int mf = 0; mf < 4; ++mf)
#pragma unroll
      for (int g = 0; g < 3; ++g) acc[mf][g] = (f32x4)(0.f);

    char* buf = &AsB[cur][0];
    __builtin_amdgcn_s_setprio(1);
#pragma unroll
    for (int ks = 0; ks < 8; ++ks) {
      s16x8 afr[4];
#pragma unroll
      for (int mf = 0; mf < 4; ++mf) {
        int row = mf * 16 + col;
        afr[mf] = *(const s16x8*)(buf + row * 512 + ((ks * 64 + kg * 16) ^ ((row & 7) << 4)));
      }
#pragma unroll
      for (int g = 0; g < 3; ++g)
#pragma unroll
        for (int mf = 0; mf < 4; ++mf)
          acc[mf][g] = __builtin_amdgcn_mfma_f32_16x16x32_bf16(afr[mf], breg[g][ks], acc[mf][g], 0, 0, 0);
    }
    __builtin_amdgcn_s_setprio(0);
    __syncthreads();                          // all waves done READING buf

    // epilogue: act -> bf16 -> staging in dead buf (first 16KB), swizzled
    int m0 = t * BM;
#pragma unroll
    for (int mf = 0; mf < 4; ++mf) {
      int mbase = mf * 16 + kg * 4;
#pragma unroll
      for (int r = 0; r < 4; ++r) {
        int mloc = mbase + r;
        int m = m0 + mloc;
        int mc = m < M ? m : M - 1;
        int n = mc >> lgL;
        float o0 = acc[mf][0][r] + bz0 + CI0[n * 128 + f];
        float o1 = acc[mf][1][r] + bz1 + CI1[n * 128 + f];
        float o2 = acc[mf][2][r] + bz2;
        __hip_bfloat16 h = __float2bfloat16(gated_act(o0, o1, o2));
        *(short*)(buf + mloc * 256 + ((f * 2) ^ ((mloc & 7) << 4))) = *(short*)&h;
      }
    }
    __syncthreads();                          // staging complete
    // cooperative coalesced store: full 256B rows, 2 passes x 512 threads x 16B
#pragma unroll
    for (int p = 0; p < 2; ++p) {
      int idx = p * 512 + tid;
      int row = idx >> 4;
      int off = (idx & 15) * 16;
      int m = m0 + row;
      if (m < M) {
        s16x8 v = *(const s16x8*)(buf + row * 256 + (off ^ ((row & 7) << 4)));
        *(s16x8*)((char*)out + (size_t)m * 256 + off) = v;
      }
    }
    __syncthreads();                          // staging reads done -> buf restageable
    cur ^= 1;
  }
}

// fused tail: layers 6,7,8 + head, per-window. 2 windows per block, 256 threads.
__global__ __launch_bounds__(256) void k_tail(
    const __hip_bfloat16* __restrict__ H8,       // [6400][128], m = n*8+j
    const __hip_bfloat16* __restrict__ W2b,      // W2 + blk*8*384*256
    const float* __restrict__ cb,                // convL_b + blk*8*3*128
    const float* __restrict__ CIb,               // CI + blk*9*2*NWIN*F
    const float* __restrict__ pw_, const float* __restrict__ pb_,
    const float* __restrict__ mw_, const float* __restrict__ mb_,
    const float* __restrict__ sw_, const float* __restrict__ sb_,
    const float* __restrict__ eps_, const float* __restrict__ signal,
    float* __restrict__ prev_next, float* __restrict__ out_mean,
    float* __restrict__ out_logvar, float* __restrict__ out_tails) {
  int b = blockIdx.x;                 // 400
  int tid = threadIdx.x;
  int w = tid >> 7, f = tid & 127;
  int n = b * 2 + w;
  __shared__ float hbuf[2][8][128];
  __shared__ float red[4][4];
  for (int idx = tid; idx < 2 * 8 * 128; idx += 256) {
    int ww = idx >> 10, rem = idx & 1023, j = rem >> 7, c = rem & 127;
    hbuf[ww][j][c] = bf2f(*(const short*)(H8 + ((size_t)((b * 2 + ww) * 8 + j)) * 128 + c));
  }
  __syncthreads();

#pragma unroll
  for (int l = 6; l <= 8; ++l) {
    const int lm = l - 1;
    const int rows = 256 >> l;                   // 4,2,1
    const __hip_bfloat16* Wl = W2b + (size_t)lm * 384 * 256;
    const float* bb = cb + (size_t)lm * 3 * 128;
    const float* ciA = CIb + ((size_t)(l * 2 + 0) * NWIN + n) * F;
    const float* ciB = CIb + ((size_t)(l * 2 + 1) * NWIN + n) * F;
    float o[4][3];
#pragma unroll
    for (int g = 0; g < 3; ++g) {
      float acc[4];
#pragma unroll
      for (int j = 0; j < 4; ++j) acc[j] = bb[g * 128 + f];
      const __hip_bfloat16* wrow = Wl + (size_t)(g * 128 + f) * 256;
#pragma unroll
      for (int k2 = 0; k2 < 2; ++k2) {
#pragma unroll 4
        for (int ch = 0; ch < 16; ++ch) {
          s16x8 wv = *(const s16x8*)(wrow + k2 * 128 + ch * 8);
          float wf[8];
#pragma unroll
          for (int e = 0; e < 8; ++e) wf[e] = bf2f(wv[e]);
#pragma unroll
          for (int j = 0; j < 4; ++j) {
            if (j < rows) {
              const float* hr = &hbuf[w][2 * j + k2][ch * 8];
#pragma unroll
              for (int e = 0; e < 8; ++e) acc[j] += wf[e] * hr[e];
            }
          }
        }
      }
#pragma unroll
      for (int j = 0; j < 4; ++j) o[j][g] = acc[j];
    }
    float newh[4];
#pragma unroll
    for (int j = 0; j < 4; ++j)
      if (j < rows) newh[j] = gated_act(o[j][0] + ciA[f], o[j][1] + ciB[f], o[j][2]);
    __syncthreads();
#pragma unroll
    for (int j = 0; j < 4; ++j)
      if (j < rows) hbuf[w][j][f] = newh[j];
    __syncthreads();
  }

  // head: pre[o] = relu(h . pre_w[o] + pre_b[o]) for both windows, o = tid
  const float* wr = pw_ + (size_t)tid * 128;
  float mc[2], vc[2];
#pragma unroll
  for (int ww = 0; ww < 2; ++ww) {
    float s = pb_[tid];
#pragma unroll 16
    for (int c = 0; c < 128; ++c) s += hbuf[ww][0][c] * wr[c];
    float p = fmaxf(s, 0.f);
    mc[ww] = p * mw_[tid];
    vc[ww] = p * sw_[tid];
  }
#pragma unroll
  for (int off = 32; off > 0; off >>= 1) {
    mc[0] += __shfl_down(mc[0], off);
    vc[0] += __shfl_down(vc[0], off);
    mc[1] += __shfl_down(mc[1], off);
    vc[1] += __shfl_down(vc[1], off);
  }
  int wv4 = tid >> 6;
  if ((tid & 63) == 0) {
    red[wv4][0] = mc[0]; red[wv4][1] = vc[0];
    red[wv4][2] = mc[1]; red[wv4][3] = vc[1];
  }
  __syncthreads();
  if (tid == 0) {
#pragma unroll
    for (int ww = 0; ww < 2; ++ww) {
      int nn = b * 2 + ww;
      float mean = red[0][ww * 2] + red[1][ww * 2] + red[2][ww * 2] + red[3][ww * 2] + mb_[0];
      float logv = red[0][ww * 2 + 1] + red[1][ww * 2 + 1] + red[2][ww * 2 + 1] + red[3][ww * 2 + 1] + sb_[0];
      float nx = eps_[nn] * expf(0.5f * logv) + mean;
      if (prev_next) prev_next[RFS + nn] = nx;
      if (out_mean) { out_mean[nn] = mean; out_logvar[nn] = logv; }
      if (nn >= NWIN - RFS) out_tails[nn - (NWIN - RFS)] = nx;
    }
  }
  if (prev_next && tid < 2 && (b * 2 + tid) < RFS)
    prev_next[b * 2 + tid] = signal[b * 2 + tid];
}

// ---------------- host ----------------

extern "C" void kernel_launch(void* const* d_in, const int* in_sizes, int n_in,
                              void* d_out, int out_size, void* d_ws, size_t ws_size,
                              hipStream_t stream) {
  const float* mgc      = (const float*)d_in[0];
  const float* signal   = (const float*)d_in[1];
  const float* cond_w   = (const float*)d_in[2];
  const float* cond_b   = (const float*)d_in[3];
  const float* conv0_w  = (const float*)d_in[4];
  const float* conv0_b  = (const float*)d_in[5];
  const float* convL_w  = (const float*)d_in[6];
  const float* convL_b  = (const float*)d_in[7];
  const float* condlin_w= (const float*)d_in[8];
  const float* condlin_b= (const float*)d_in[9];
  const float* pre_w    = (const float*)d_in[10];
  const float* pre_b    = (const float*)d_in[11];
  const float* mean_w   = (const float*)d_in[12];
  const float* mean_b   = (const float*)d_in[13];
  const float* std_w    = (const float*)d_in[14];
  const float* std_b    = (const float*)d_in[15];
  const float* eps      = (const float*)d_in[16];
  float* out = (float*)d_out;

  float* wsf   = (float*)d_ws;
  float* cond  = wsf;                          // 48,000 f
  float* CI    = cond + 48000;                 // 7,372,800 f
  float* prevb = CI + 7372800;                 // 5,248 f
  float* CV    = prevb + 5248;                 // 503,040 f
  float* base  = CV + 503040;
  __hip_bfloat16* W2   = (__hip_bfloat16*)base;            // 3,145,728 bf16
  __hip_bfloat16* bufA = W2 + 3145728;                     // 26,214,400 + slack
  __hip_bfloat16* bufB = bufA + 26214400 + 65536;          // 13,107,200 + slack

  k_cond<<<(NWIN * MGCS + 255) / 256, 256, 0, stream>>>(mgc, cond_w, cond_b, cond);
  k_ci<<<dim3(72, 7), 256, 0, stream>>>(cond, condlin_w, condlin_b, CI);
  k_wt<<<(NBLK * 8 * 384 * 256 + 255) / 256, 256, 0, stream>>>(convL_w, W2);
  k_outsig<<<(NWIN + 255) / 256, 256, 0, stream>>>(signal, out);

  for (int blk = 0; blk < NBLK; ++blk) {
    const float* prev = (blk == 0) ? signal : (prevb + (size_t)(blk - 1) * 1312);
    const float* CIb = CI + (size_t)(blk * NLAY) * 2 * NWIN * F;
    k_pre0<<<(1310 * 384 + 255) / 256, 256, 0, stream>>>(
        prev, conv0_w + (size_t)blk * 3 * F * 2, conv0_b + (size_t)blk * 3 * F, CV);
    k_layer0<<<(NWIN * 256 * 16 + 255) / 256, 256, 0, stream>>>(CV, CIb, bufA);

    __hip_bfloat16* cur = bufA;
    __hip_bfloat16* nxt = bufB;
    for (int l = 1; l <= 5; ++l) {             // layers 1..5 via MFMA GEMM
      int Lout = 256 >> l;
      int M = NWIN * Lout;
      const float* ci0 = CI + ((size_t)((blk * NLAY + l) * 2 + 0)) * NWIN * F;
      const float* ci1 = CI + ((size_t)((blk * NLAY + l) * 2 + 1)) * NWIN * F;
      const __hip_bfloat16* wt = W2 + (size_t)(blk * 8 + (l - 1)) * 384 * 256;
      const float* bs = convL_b + (size_t)((blk * 8 + (l - 1)) * 3) * F;
      int ntiles = (M + BM - 1) / BM;
      int gx = ntiles < 512 ? ntiles : 512;
      k_gemm<<<dim3(gx), 512, 0, stream>>>(cur, wt, bs, ci0, ci1, nxt, M, 8 - l);
      __hip_bfloat16* tmp = cur; cur = nxt; nxt = tmp;
    }
    // cur now holds l=5 output [6400][128]; fused layers 6-8 + head
    k_tail<<<400, 256, 0, stream>>>(
        cur, W2 + (size_t)blk * 8 * 384 * 256,
        convL_b + (size_t)blk * 8 * 3 * F, CIb,
        pre_w + (size_t)blk * 256 * F, pre_b + (size_t)blk * 256,
        mean_w + (size_t)blk * 256, mean_b + blk,
        std_w + (size_t)blk * 256, std_b + blk,
        eps + (size_t)blk * NWIN, signal,
        (blk < 3) ? (prevb + (size_t)blk * 1312) : nullptr,
        (blk == 3) ? (out + 800) : nullptr,
        (blk == 3) ? (out + 1600) : nullptr,
        out + 2400 + (size_t)blk * 512);
  }
}

// Round 8
// 778.309 us; speedup vs baseline: 1.2423x; 1.2423x over previous
//
#include <hip/hip_runtime.h>
#include <hip/hip_bf16.h>

#define F 128
#define MGCS 60
#define NWIN 800
#define RFS 512
#define NBLK 4
#define NLAY 9
#define SQF 0.70710678118f

typedef __attribute__((ext_vector_type(8))) short s16x8;
typedef __attribute__((ext_vector_type(4))) float f32x4;

#define VMCNT(n) asm volatile("s_waitcnt vmcnt(" #n ")" ::: "memory")

__device__ __forceinline__ float gated_act(float o0, float o1, float o2) {
  o0 = fminf(fmaxf(o0, -21.f), 21.f);
  o1 = fminf(fmaxf(o1, -21.f), 21.f);
  float a = __expf(2.f * o0);
  float b = __expf(-o1);
  float r = (a - 1.f) * __builtin_amdgcn_rcpf((a + 1.f) * (1.f + b));
  return (r + o2) * SQF;
}

__device__ __forceinline__ float bf2f(short s) {
  union { unsigned u; float f; } t;
  t.u = ((unsigned)(unsigned short)s) << 16;
  return t.f;
}

// ---------------- precompute kernels ----------------

__global__ void k_cond(const float* __restrict__ mgc, const float* __restrict__ cond_w,
                       const float* __restrict__ cond_b, float* __restrict__ cond) {
  int i = blockIdx.x * blockDim.x + threadIdx.x;
  if (i >= NWIN * MGCS) return;
  int n = i / MGCS, m = i % MGCS;
  int t = n / 200, u = n % 200;
  const float* wrow = cond_w + (size_t)(u * MGCS + m) * MGCS;
  const float* mr = mgc + t * MGCS;
  float s = cond_b[u * MGCS + m];
#pragma unroll
  for (int k = 0; k < MGCS; ++k) s += mr[k] * wrow[k];
  cond[i] = tanhf(s);
}

__global__ __launch_bounds__(256) void k_ci(
    const float* __restrict__ cond, const float* __restrict__ clw,
    const float* __restrict__ clb, float* __restrict__ CI) {
  int w = blockIdx.x;
  int n0 = blockIdx.y * 128;
  __shared__ float wsh[128][61];
  __shared__ float csh[128][61];
  int tid = threadIdx.x;
  for (int idx = tid; idx < 128 * MGCS; idx += 256) {
    int f = idx / MGCS, k = idx % MGCS;
    wsh[f][k] = clw[((size_t)w * 128 + f) * MGCS + k];
  }
  for (int idx = tid; idx < 128 * MGCS; idx += 256) {
    int n = idx / MGCS, k = idx % MGCS;
    csh[n][k] = (n0 + n < NWIN) ? cond[(n0 + n) * MGCS + k] : 0.f;
  }
  __syncthreads();
  int tn = tid >> 4, tf = tid & 15;
  float acc[8][8] = {};
  for (int k = 0; k < MGCS; ++k) {
    float a[8], b[8];
#pragma unroll
    for (int i = 0; i < 8; ++i) a[i] = csh[i * 16 + tn][k];
#pragma unroll
    for (int j = 0; j < 8; ++j) b[j] = wsh[j * 16 + tf][k];
#pragma unroll
    for (int i = 0; i < 8; ++i)
#pragma unroll
      for (int j = 0; j < 8; ++j) acc[i][j] += a[i] * b[j];
  }
  float bb[8];
#pragma unroll
  for (int j = 0; j < 8; ++j) bb[j] = clb[w * 128 + j * 16 + tf];
#pragma unroll
  for (int i = 0; i < 8; ++i) {
    int n = n0 + i * 16 + tn;
    if (n < NWIN) {
#pragma unroll
      for (int j = 0; j < 8; ++j)
        CI[((size_t)w * NWIN + n) * 128 + j * 16 + tf] = acc[i][j] + bb[j];
    }
  }
}

__global__ void k_wt(const float* __restrict__ convL_w, __hip_bfloat16* __restrict__ W2) {
  int i = blockIdx.x * blockDim.x + threadIdx.x;
  const int total = NBLK * 8 * 384 * 256;
  if (i >= total) return;
  int k = i & 255;
  int tf = (i >> 8) % 384;
  int wl = i / (384 * 256);
  int t = tf >> 7, f = tf & 127;
  int k2 = k >> 7, c = k & 127;
  W2[i] = __float2bfloat16(convL_w[(((size_t)(wl * 3 + t) * 128 + f) * 128 + c) * 2 + k2]);
}

// PW[blk][o][c] bf16 = pre_w
__global__ void k_wt2(const float* __restrict__ pre_w, __hip_bfloat16* __restrict__ PW) {
  int i = blockIdx.x * blockDim.x + threadIdx.x;
  if (i < NBLK * 256 * 128) PW[i] = __float2bfloat16(pre_w[i]);
}

__global__ void k_outsig(const float* __restrict__ signal, float* __restrict__ out) {
  int i = blockIdx.x * blockDim.x + threadIdx.x;
  if (i < NWIN) out[i] = signal[RFS + i];
}

// ---------------- per-block kernels ----------------

__global__ void k_pre0(const float* __restrict__ prev, const float* __restrict__ w0,
                       const float* __restrict__ b0, float* __restrict__ CV) {
  int i = blockIdx.x * blockDim.x + threadIdx.x;
  if (i >= 1310 * 384) return;
  int tf = i % 384, s = i / 384;
  CV[i] = b0[tf] + prev[s] * w0[tf * 2] + prev[s + 1] * w0[tf * 2 + 1];
}

__global__ void k_layer0(const float* __restrict__ CV, const float* __restrict__ CIb,
                         __hip_bfloat16* __restrict__ out) {
  int i = blockIdx.x * blockDim.x + threadIdx.x;
  if (i >= NWIN * 256 * 16) return;
  int fg = i & 15;
  int rest = i >> 4;
  int j = rest & 255;
  int n = rest >> 8;
  int f0 = fg * 8;
  const float* cv = CV + (size_t)(n + 2 * j) * 384;
  const float* ci = CIb + (size_t)n * F;
  float4 c0a = *(const float4*)(cv + f0),       c0b = *(const float4*)(cv + f0 + 4);
  float4 c1a = *(const float4*)(cv + 128 + f0), c1b = *(const float4*)(cv + 132 + f0);
  float4 c2a = *(const float4*)(cv + 256 + f0), c2b = *(const float4*)(cv + 260 + f0);
  float4 i0a = *(const float4*)(ci + f0),       i0b = *(const float4*)(ci + f0 + 4);
  float4 i1a = *(const float4*)(ci + (size_t)NWIN * F + f0);
  float4 i1b = *(const float4*)(ci + (size_t)NWIN * F + f0 + 4);
  s16x8 res;
#pragma unroll
  for (int e = 0; e < 8; ++e) {
    float o0 = ((e < 4) ? (&c0a.x)[e] : (&c0b.x)[e - 4]) + ((e < 4) ? (&i0a.x)[e] : (&i0b.x)[e - 4]);
    float o1 = ((e < 4) ? (&c1a.x)[e] : (&c1b.x)[e - 4]) + ((e < 4) ? (&i1a.x)[e] : (&i1b.x)[e - 4]);
    float o2 = (e < 4) ? (&c2a.x)[e] : (&c2b.x)[e - 4];
    __hip_bfloat16 h = __float2bfloat16(gated_act(o0, o1, o2));
    res[e] = *(short*)&h;
  }
  *(s16x8*)(out + ((size_t)(n * 256 + j)) * F + f0) = res;
}

// Weight-stationary persistent MFMA GEMM (layers 1..5). Unchanged from R6.
#define BM 64
__global__ __launch_bounds__(512, 2) void k_gemm(
    const __hip_bfloat16* __restrict__ A, const __hip_bfloat16* __restrict__ W2,
    const float* __restrict__ bias, const float* __restrict__ CI0,
    const float* __restrict__ CI1, __hip_bfloat16* __restrict__ out,
    int M, int lgL) {
  __shared__ char AsB[2][BM * 512];
  const int tid = threadIdx.x;
  const int lane = tid & 63, wid = tid >> 6;
  const int ntiles = (M + BM - 1) / BM;
  const int gdx = gridDim.x;
  const int col = lane & 15, kg = lane >> 4;

  const char* Wb = (const char*)W2;
  const int f = wid * 16 + col;
  s16x8 breg[3][8];
#pragma unroll
  for (int g = 0; g < 3; ++g)
#pragma unroll
    for (int ks = 0; ks < 8; ++ks)
      breg[g][ks] = *(const s16x8*)(Wb + (size_t)(g * 128 + f) * 512 + ks * 64 + kg * 16);
  const float bz0 = bias[f], bz1 = bias[128 + f], bz2 = bias[256 + f];

  const char* Ab = (const char*)A;
  const int half = lane >> 5;
  const int lin = (lane & 31) * 16;
#pragma unroll
  for (int it = 0; it < 4; ++it) {
    int inst = wid * 4 + it;
    int row = inst * 2 + half;
    const char* src = Ab + (size_t)blockIdx.x * (BM * 512) + row * 512 + (lin ^ ((row & 7) << 4));
    __builtin_amdgcn_global_load_lds(
        (const __attribute__((address_space(1))) unsigned int*)src,
        (__attribute__((address_space(3))) unsigned int*)(&AsB[0][0] + inst * 1024), 16, 0, 0);
  }

  int cur = 0;
  for (int t = blockIdx.x; t < ntiles; t += gdx) {
    int tn = t + gdx;
    if (tn < ntiles) {
      char* dst = &AsB[cur ^ 1][0];
#pragma unroll
      for (int it = 0; it < 4; ++it) {
        int inst = wid * 4 + it;
        int row = inst * 2 + half;
        const char* src = Ab + (size_t)tn * (BM * 512) + row * 512 + (lin ^ ((row & 7) << 4));
        __builtin_amdgcn_global_load_lds(
            (const __attribute__((address_space(1))) unsigned int*)src,
            (__attribute__((address_space(3))) unsigned int*)(dst + inst * 1024), 16, 0, 0);
      }
      VMCNT(4);
    } else {
      VMCNT(0);
    }
    __builtin_amdgcn_s_barrier();
    __builtin_amdgcn_sched_barrier(0);

    f32x4 acc[4][3];
#pragma unroll
    for (int mf = 0; mf < 4; ++mf)
#pragma unroll
      for (int g = 0; g < 3; ++g) acc[mf][g] = (f32x4)(0.f);

    char* buf = &AsB[cur][0];
    __builtin_amdgcn_s_setprio(1);
#pragma unroll
    for (int ks = 0; ks < 8; ++ks) {
      s16x8 afr[4];
#pragma unroll
      for (int mf = 0; mf < 4; ++mf) {
        int row = mf * 16 + col;
        afr[mf] = *(const s16x8*)(buf + row * 512 + ((ks * 64 + kg * 16) ^ ((row & 7) << 4)));
      }
#pragma unroll
      for (int g = 0; g < 3; ++g)
#pragma unroll
        for (int mf = 0; mf < 4; ++mf)
          acc[mf][g] = __builtin_amdgcn_mfma_f32_16x16x32_bf16(afr[mf], breg[g][ks], acc[mf][g], 0, 0, 0);
    }
    __builtin_amdgcn_s_setprio(0);
    __syncthreads();

    int m0 = t * BM;
#pragma unroll
    for (int mf = 0; mf < 4; ++mf) {
      int mbase = mf * 16 + kg * 4;
#pragma unroll
      for (int r = 0; r < 4; ++r) {
        int mloc = mbase + r;
        int m = m0 + mloc;
        int mc = m < M ? m : M - 1;
        int n = mc >> lgL;
        float o0 = acc[mf][0][r] + bz0 + CI0[n * 128 + f];
        float o1 = acc[mf][1][r] + bz1 + CI1[n * 128 + f];
        float o2 = acc[mf][2][r] + bz2;
        __hip_bfloat16 h = __float2bfloat16(gated_act(o0, o1, o2));
        *(short*)(buf + mloc * 256 + ((f * 2) ^ ((mloc & 7) << 4))) = *(short*)&h;
      }
    }
    __syncthreads();
#pragma unroll
    for (int p = 0; p < 2; ++p) {
      int idx = p * 512 + tid;
      int row = idx >> 4;
      int off = (idx & 15) * 16;
      int m = m0 + row;
      if (m < M) {
        s16x8 v = *(const s16x8*)(buf + row * 256 + (off ^ ((row & 7) << 4)));
        *(s16x8*)((char*)out + (size_t)m * 256 + off) = v;
      }
    }
    __syncthreads();
    cur ^= 1;
  }
}

// ---- MFMA tail: one layer (RIN input rows/window -> RIN/2), 8 windows/block ----
// hsrc/hdst: LDS bf16 tiles, row stride 256B, XOR-swizzled by ((row&7)<<4).
template <int MF, int RIN>
__device__ __forceinline__ void tail_layer(
    const char* hsrc, char* hdst, const __hip_bfloat16* Wl, const float* bb,
    const float* ciA, const float* ciB, int b, int w4, int lane) {
  const int col = lane & 15, kg = lane >> 4;
  constexpr int ROUT = RIN / 2;
  constexpr int MV = 8 * ROUT;                  // valid output rows
  f32x4 acc[MF][2][3];
#pragma unroll
  for (int mf = 0; mf < MF; ++mf)
#pragma unroll
    for (int ff = 0; ff < 2; ++ff)
#pragma unroll
      for (int g = 0; g < 3; ++g) acc[mf][ff][g] = (f32x4)(0.f);
  const char* Wb = (const char*)Wl;
#pragma unroll
  for (int ks = 0; ks < 8; ++ks) {
    s16x8 afr[MF];
    int ke = ks * 32 + kg * 8;
    int k2 = ke >> 7, c = ke & 127;
#pragma unroll
    for (int mf = 0; mf < MF; ++mf) {
      int m = mf * 16 + col;
      int mm = m < MV ? m : MV - 1;
      int win = mm / ROUT, jp = mm % ROUT;
      int srow = win * RIN + 2 * jp + k2;
      afr[mf] = *(const s16x8*)(hsrc + srow * 256 + ((c * 2) ^ ((srow & 7) << 4)));
    }
#pragma unroll
    for (int g = 0; g < 3; ++g)
#pragma unroll
      for (int ff = 0; ff < 2; ++ff) {
        int f = w4 * 32 + ff * 16 + col;
        s16x8 bfr = *(const s16x8*)(Wb + (size_t)(g * 128 + f) * 512 + ks * 64 + kg * 16);
#pragma unroll
        for (int mf = 0; mf < MF; ++mf)
          acc[mf][ff][g] = __builtin_amdgcn_mfma_f32_16x16x32_bf16(afr[mf], bfr, acc[mf][ff][g], 0, 0, 0);
      }
  }
#pragma unroll
  for (int mf = 0; mf < MF; ++mf)
#pragma unroll
    for (int ff = 0; ff < 2; ++ff) {
      int f = w4 * 32 + ff * 16 + col;
      float b0 = bb[f], b1 = bb[128 + f], b2 = bb[256 + f];
#pragma unroll
      for (int r = 0; r < 4; ++r) {
        int m = mf * 16 + kg * 4 + r;
        if (m < MV) {
          int win = m / ROUT;
          int n = b * 8 + win;
          float o0 = acc[mf][ff][0][r] + b0 + ciA[n * 128 + f];
          float o1 = acc[mf][ff][1][r] + b1 + ciB[n * 128 + f];
          float o2 = acc[mf][ff][2][r] + b2;
          __hip_bfloat16 h = __float2bfloat16(gated_act(o0, o1, o2));
          *(short*)(hdst + m * 256 + ((f * 2) ^ ((m & 7) << 4))) = *(short*)&h;
        }
      }
    }
}

// fused tail: layers 6,7,8 + head. 8 windows/block, 100 blocks, 256 threads.
__global__ __launch_bounds__(256) void k_tail(
    const __hip_bfloat16* __restrict__ H8,       // [6400][128], row = n*8+j
    const __hip_bfloat16* __restrict__ W2b,      // W2 + blk*8*384*256
    const float* __restrict__ cb,                // convL_b + blk*8*3*128
    const float* __restrict__ CIb,               // CI + blk*9*2*NWIN*F
    const __hip_bfloat16* __restrict__ PWb,      // PW + blk*256*128 (bf16)
    const float* __restrict__ pb_,
    const float* __restrict__ mw_, const float* __restrict__ mb_,
    const float* __restrict__ sw_, const float* __restrict__ sb_,
    const float* __restrict__ eps_, const float* __restrict__ signal,
    float* __restrict__ prev_next, float* __restrict__ out_mean,
    float* __restrict__ out_logvar, float* __restrict__ out_tails) {
  __shared__ char hA[64 * 256];
  __shared__ char hB[32 * 256];
  __shared__ float psm[8][256];
  __shared__ float psv[8][256];
  const int b = blockIdx.x;
  const int tid = threadIdx.x;
  const int lane = tid & 63, w4 = tid >> 6;
  const int col = lane & 15, kg = lane >> 4;

  // load 64 rows (8 win x 8) of l=5 output, swizzled
  {
    const char* src = (const char*)(H8 + (size_t)b * 64 * 128);
#pragma unroll
    for (int p = 0; p < 4; ++p) {
      int idx = p * 256 + tid;                   // 1024 chunks of 16B
      int row = idx >> 4;
      int off = (idx & 15) * 16;
      s16x8 v = *(const s16x8*)(src + row * 256 + off);
      *(s16x8*)(hA + row * 256 + (off ^ ((row & 7) << 4))) = v;
    }
  }
  __syncthreads();

  // layer 6: 64 -> 32 rows (hA -> hB)
  tail_layer<2, 8>(hA, hB, W2b + (size_t)5 * 384 * 256, cb + (size_t)5 * 384,
                   CIb + (size_t)(6 * 2 + 0) * NWIN * F, CIb + (size_t)(6 * 2 + 1) * NWIN * F,
                   b, w4, lane);
  __syncthreads();
  // layer 7: 32 -> 16 rows (hB -> hA)
  tail_layer<1, 4>(hB, hA, W2b + (size_t)6 * 384 * 256, cb + (size_t)6 * 384,
                   CIb + (size_t)(7 * 2 + 0) * NWIN * F, CIb + (size_t)(7 * 2 + 1) * NWIN * F,
                   b, w4, lane);
  __syncthreads();
  // layer 8: 16 -> 8 rows (hA -> hB)
  tail_layer<1, 2>(hA, hB, W2b + (size_t)7 * 384 * 256, cb + (size_t)7 * 384,
                   CIb + (size_t)(8 * 2 + 0) * NWIN * F, CIb + (size_t)(8 * 2 + 1) * NWIN * F,
                   b, w4, lane);
  __syncthreads();

  // head pre-GEMM: pre[win][o] = relu(h[win] . PW[o] + pb[o]);  M=16(pad), N=256, K=128
  {
    f32x4 acc2[4];
#pragma unroll
    for (int nf = 0; nf < 4; ++nf) acc2[nf] = (f32x4)(0.f);
    const char* PB = (const char*)PWb;
#pragma unroll
    for (int ks = 0; ks < 4; ++ks) {
      int ke = ks * 32 + kg * 8;
      int m = col;
      int win = m < 8 ? m : 7;
      s16x8 afr = *(const s16x8*)(hB + win * 256 + ((ke * 2) ^ ((win & 7) << 4)));
#pragma unroll
      for (int nf = 0; nf < 4; ++nf) {
        int o = w4 * 64 + nf * 16 + col;
        s16x8 bfr = *(const s16x8*)(PB + (size_t)o * 256 + ks * 64 + kg * 16);
        acc2[nf] = __builtin_amdgcn_mfma_f32_16x16x32_bf16(afr, bfr, acc2[nf], 0, 0, 0);
      }
    }
#pragma unroll
    for (int nf = 0; nf < 4; ++nf) {
      int o = w4 * 64 + nf * 16 + col;
      float pb = pb_[o], mw = mw_[o], sw = sw_[o];
#pragma unroll
      for (int r = 0; r < 4; ++r) {
        int m = kg * 4 + r;
        if (m < 8) {
          float p = fmaxf(acc2[nf][r] + pb, 0.f);
          psm[m][o] = p * mw;
          psv[m][o] = p * sw;
        }
      }
    }
  }
  __syncthreads();

  // reduce 256 -> scalar per window; tid = win*32 + l32, each sums 8 o's
  {
    int win = tid >> 5, l32 = tid & 31;
    const float* pm = &psm[win][l32 * 8];
    const float* pv = &psv[win][l32 * 8];
    float sm = 0.f, sv = 0.f;
#pragma unroll
    for (int e = 0; e < 8; ++e) { sm += pm[e]; sv += pv[e]; }
#pragma unroll
    for (int off = 16; off > 0; off >>= 1) {
      sm += __shfl_down(sm, off, 32);
      sv += __shfl_down(sv, off, 32);
    }
    if (l32 == 0) {
      int n = b * 8 + win;
      float mean = sm + mb_[0];
      float logv = sv + sb_[0];
      float nx = eps_[n] * expf(0.5f * logv) + mean;
      if (prev_next) prev_next[RFS + n] = nx;
      if (out_mean) { out_mean[n] = mean; out_logvar[n] = logv; }
      if (n >= NWIN - RFS) out_tails[n - (NWIN - RFS)] = nx;
    }
  }
  if (prev_next && tid < 8 && (b * 8 + tid) < RFS)
    prev_next[b * 8 + tid] = signal[b * 8 + tid];
}

// ---------------- host ----------------

extern "C" void kernel_launch(void* const* d_in, const int* in_sizes, int n_in,
                              void* d_out, int out_size, void* d_ws, size_t ws_size,
                              hipStream_t stream) {
  const float* mgc      = (const float*)d_in[0];
  const float* signal   = (const float*)d_in[1];
  const float* cond_w   = (const float*)d_in[2];
  const float* cond_b   = (const float*)d_in[3];
  const float* conv0_w  = (const float*)d_in[4];
  const float* conv0_b  = (const float*)d_in[5];
  const float* convL_w  = (const float*)d_in[6];
  const float* convL_b  = (const float*)d_in[7];
  const float* condlin_w= (const float*)d_in[8];
  const float* condlin_b= (const float*)d_in[9];
  const float* pre_w    = (const float*)d_in[10];
  const float* pre_b    = (const float*)d_in[11];
  const float* mean_w   = (const float*)d_in[12];
  const float* mean_b   = (const float*)d_in[13];
  const float* std_w    = (const float*)d_in[14];
  const float* std_b    = (const float*)d_in[15];
  const float* eps      = (const float*)d_in[16];
  float* out = (float*)d_out;

  float* wsf   = (float*)d_ws;
  float* cond  = wsf;                          // 48,000 f
  float* CI    = cond + 48000;                 // 7,372,800 f
  float* prevb = CI + 7372800;                 // 5,248 f
  float* CV    = prevb + 5248;                 // 503,040 f
  float* base  = CV + 503040;
  __hip_bfloat16* W2   = (__hip_bfloat16*)base;            // 3,145,728 bf16
  __hip_bfloat16* PW   = W2 + 3145728;                     // 131,072 bf16
  __hip_bfloat16* bufA = PW + 131072;                      // 26,214,400 + slack
  __hip_bfloat16* bufB = bufA + 26214400 + 65536;          // 13,107,200 + slack

  k_cond<<<(NWIN * MGCS + 255) / 256, 256, 0, stream>>>(mgc, cond_w, cond_b, cond);
  k_ci<<<dim3(72, 7), 256, 0, stream>>>(cond, condlin_w, condlin_b, CI);
  k_wt<<<(NBLK * 8 * 384 * 256 + 255) / 256, 256, 0, stream>>>(convL_w, W2);
  k_wt2<<<(NBLK * 256 * 128 + 255) / 256, 256, 0, stream>>>(pre_w, PW);
  k_outsig<<<(NWIN + 255) / 256, 256, 0, stream>>>(signal, out);

  for (int blk = 0; blk < NBLK; ++blk) {
    const float* prev = (blk == 0) ? signal : (prevb + (size_t)(blk - 1) * 1312);
    const float* CIb = CI + (size_t)(blk * NLAY) * 2 * NWIN * F;
    k_pre0<<<(1310 * 384 + 255) / 256, 256, 0, stream>>>(
        prev, conv0_w + (size_t)blk * 3 * F * 2, conv0_b + (size_t)blk * 3 * F, CV);
    k_layer0<<<(NWIN * 256 * 16 + 255) / 256, 256, 0, stream>>>(CV, CIb, bufA);

    __hip_bfloat16* cur = bufA;
    __hip_bfloat16* nxt = bufB;
    for (int l = 1; l <= 5; ++l) {
      int Lout = 256 >> l;
      int M = NWIN * Lout;
      const float* ci0 = CI + ((size_t)((blk * NLAY + l) * 2 + 0)) * NWIN * F;
      const float* ci1 = CI + ((size_t)((blk * NLAY + l) * 2 + 1)) * NWIN * F;
      const __hip_bfloat16* wt = W2 + (size_t)(blk * 8 + (l - 1)) * 384 * 256;
      const float* bs = convL_b + (size_t)((blk * 8 + (l - 1)) * 3) * F;
      int ntiles = (M + BM - 1) / BM;
      int gx = ntiles < 512 ? ntiles : 512;
      k_gemm<<<dim3(gx), 512, 0, stream>>>(cur, wt, bs, ci0, ci1, nxt, M, 8 - l);
      __hip_bfloat16* tmp = cur; cur = nxt; nxt = tmp;
    }
    // cur holds l=5 output [6400][128]; fused MFMA layers 6-8 + head
    k_tail<<<100, 256, 0, stream>>>(
        cur, W2 + (size_t)blk * 8 * 384 * 256,
        convL_b + (size_t)blk * 8 * 3 * F, CIb,
        PW + (size_t)blk * 256 * 128, pre_b + (size_t)blk * 256,
        mean_w + (size_t)blk * 256, mean_b + blk,
        std_w + (size_t)blk * 256, std_b + blk,
        eps + (size_t)blk * NWIN, signal,
        (blk < 3) ? (prevb + (size_t)blk * 1312) : nullptr,
        (blk == 3) ? (out + 800) : nullptr,
        (blk == 3) ? (out + 1600) : nullptr,
        out + 2400 + (size_t)blk * 512);
  }
}

// Round 9
// 766.278 us; speedup vs baseline: 1.2618x; 1.0157x over previous
//
#include <hip/hip_runtime.h>
#include <hip/hip_bf16.h>

#define F 128
#define MGCS 60
#define NWIN 800
#define RFS 512
#define NBLK 4
#define NLAY 9
#define SQF 0.70710678118f

typedef __attribute__((ext_vector_type(8))) short s16x8;
typedef __attribute__((ext_vector_type(4))) float f32x4;

#define VMCNT(n) asm volatile("s_waitcnt vmcnt(" #n ")" ::: "memory")

__device__ __forceinline__ float gated_act(float o0, float o1, float o2) {
  o0 = fminf(fmaxf(o0, -21.f), 21.f);
  o1 = fminf(fmaxf(o1, -21.f), 21.f);
  float a = __expf(2.f * o0);
  float b = __expf(-o1);
  float r = (a - 1.f) * __builtin_amdgcn_rcpf((a + 1.f) * (1.f + b));
  return (r + o2) * SQF;
}

__device__ __forceinline__ float bf2f(short s) {
  union { unsigned u; float f; } t;
  t.u = ((unsigned)(unsigned short)s) << 16;
  return t.f;
}

// ---------------- precompute kernels ----------------

__global__ void k_cond(const float* __restrict__ mgc, const float* __restrict__ cond_w,
                       const float* __restrict__ cond_b, float* __restrict__ cond) {
  int i = blockIdx.x * blockDim.x + threadIdx.x;
  if (i >= NWIN * MGCS) return;
  int n = i / MGCS, m = i % MGCS;
  int t = n / 200, u = n % 200;
  const float* wrow = cond_w + (size_t)(u * MGCS + m) * MGCS;
  const float* mr = mgc + t * MGCS;
  float s = cond_b[u * MGCS + m];
#pragma unroll
  for (int k = 0; k < MGCS; ++k) s += mr[k] * wrow[k];
  cond[i] = tanhf(s);
}

__global__ __launch_bounds__(256) void k_ci(
    const float* __restrict__ cond, const float* __restrict__ clw,
    const float* __restrict__ clb, float* __restrict__ CI) {
  int w = blockIdx.x;
  int n0 = blockIdx.y * 128;
  __shared__ float wsh[128][61];
  __shared__ float csh[128][61];
  int tid = threadIdx.x;
  for (int idx = tid; idx < 128 * MGCS; idx += 256) {
    int f = idx / MGCS, k = idx % MGCS;
    wsh[f][k] = clw[((size_t)w * 128 + f) * MGCS + k];
  }
  for (int idx = tid; idx < 128 * MGCS; idx += 256) {
    int n = idx / MGCS, k = idx % MGCS;
    csh[n][k] = (n0 + n < NWIN) ? cond[(n0 + n) * MGCS + k] : 0.f;
  }
  __syncthreads();
  int tn = tid >> 4, tf = tid & 15;
  float acc[8][8] = {};
  for (int k = 0; k < MGCS; ++k) {
    float a[8], b[8];
#pragma unroll
    for (int i = 0; i < 8; ++i) a[i] = csh[i * 16 + tn][k];
#pragma unroll
    for (int j = 0; j < 8; ++j) b[j] = wsh[j * 16 + tf][k];
#pragma unroll
    for (int i = 0; i < 8; ++i)
#pragma unroll
      for (int j = 0; j < 8; ++j) acc[i][j] += a[i] * b[j];
  }
  float bb[8];
#pragma unroll
  for (int j = 0; j < 8; ++j) bb[j] = clb[w * 128 + j * 16 + tf];
#pragma unroll
  for (int i = 0; i < 8; ++i) {
    int n = n0 + i * 16 + tn;
    if (n < NWIN) {
#pragma unroll
      for (int j = 0; j < 8; ++j)
        CI[((size_t)w * NWIN + n) * 128 + j * 16 + tf] = acc[i][j] + bb[j];
    }
  }
}

__global__ void k_wt(const float* __restrict__ convL_w, __hip_bfloat16* __restrict__ W2) {
  int i = blockIdx.x * blockDim.x + threadIdx.x;
  const int total = NBLK * 8 * 384 * 256;
  if (i >= total) return;
  int k = i & 255;
  int tf = (i >> 8) % 384;
  int wl = i / (384 * 256);
  int t = tf >> 7, f = tf & 127;
  int k2 = k >> 7, c = k & 127;
  W2[i] = __float2bfloat16(convL_w[(((size_t)(wl * 3 + t) * 128 + f) * 128 + c) * 2 + k2]);
}

__global__ void k_wt2(const float* __restrict__ pre_w, __hip_bfloat16* __restrict__ PW) {
  int i = blockIdx.x * blockDim.x + threadIdx.x;
  if (i < NBLK * 256 * 128) PW[i] = __float2bfloat16(pre_w[i]);
}

__global__ void k_outsig(const float* __restrict__ signal, float* __restrict__ out) {
  int i = blockIdx.x * blockDim.x + threadIdx.x;
  if (i < NWIN) out[i] = signal[RFS + i];
}

// ---------------- per-block kernels ----------------

__global__ void k_pre0(const float* __restrict__ prev, const float* __restrict__ w0,
                       const float* __restrict__ b0, float* __restrict__ CV) {
  int i = blockIdx.x * blockDim.x + threadIdx.x;
  if (i >= 1310 * 384) return;
  int tf = i % 384, s = i / 384;
  CV[i] = b0[tf] + prev[s] * w0[tf * 2] + prev[s + 1] * w0[tf * 2 + 1];
}

__global__ void k_layer0(const float* __restrict__ CV, const float* __restrict__ CIb,
                         __hip_bfloat16* __restrict__ out) {
  int i = blockIdx.x * blockDim.x + threadIdx.x;
  if (i >= NWIN * 256 * 16) return;
  int fg = i & 15;
  int rest = i >> 4;
  int j = rest & 255;
  int n = rest >> 8;
  int f0 = fg * 8;
  const float* cv = CV + (size_t)(n + 2 * j) * 384;
  const float* ci = CIb + (size_t)n * F;
  float4 c0a = *(const float4*)(cv + f0),       c0b = *(const float4*)(cv + f0 + 4);
  float4 c1a = *(const float4*)(cv + 128 + f0), c1b = *(const float4*)(cv + 132 + f0);
  float4 c2a = *(const float4*)(cv + 256 + f0), c2b = *(const float4*)(cv + 260 + f0);
  float4 i0a = *(const float4*)(ci + f0),       i0b = *(const float4*)(ci + f0 + 4);
  float4 i1a = *(const float4*)(ci + (size_t)NWIN * F + f0);
  float4 i1b = *(const float4*)(ci + (size_t)NWIN * F + f0 + 4);
  s16x8 res;
#pragma unroll
  for (int e = 0; e < 8; ++e) {
    float o0 = ((e < 4) ? (&c0a.x)[e] : (&c0b.x)[e - 4]) + ((e < 4) ? (&i0a.x)[e] : (&i0b.x)[e - 4]);
    float o1 = ((e < 4) ? (&c1a.x)[e] : (&c1b.x)[e - 4]) + ((e < 4) ? (&i1a.x)[e] : (&i1b.x)[e - 4]);
    float o2 = (e < 4) ? (&c2a.x)[e] : (&c2b.x)[e - 4];
    __hip_bfloat16 h = __float2bfloat16(gated_act(o0, o1, o2));
    res[e] = *(short*)&h;
  }
  *(s16x8*)(out + ((size_t)(n * 256 + j)) * F + f0) = res;
}

// One-shot MFMA GEMM: grid (2, ntiles). Block = 256 thr (4 waves), owns a
// 64-row tile x one f-half (64 f-cols, 3 gates in regs). Two independent
// blocks co-reside per CU (no inter-block barriers) -> natural phase overlap.
__global__ __launch_bounds__(256, 2) void k_gemm2(
    const __hip_bfloat16* __restrict__ A, const __hip_bfloat16* __restrict__ W2,
    const float* __restrict__ bias, const float* __restrict__ CI0,
    const float* __restrict__ CI1, __hip_bfloat16* __restrict__ out,
    int M, int lgL) {
  __shared__ char As[64 * 512];                  // 32 KB A tile (swizzled rows)
  __shared__ char Stg[64 * 128];                 // 8 KB output staging (f-half)
  const int tid = threadIdx.x;
  const int lane = tid & 63, w4 = tid >> 6;
  const int col = lane & 15, kg = lane >> 4;
  const int fh = blockIdx.x;                     // f-half: 0 or 1
  const int m0 = blockIdx.y * 64;
  const int fl = w4 * 16 + col;                  // local f in [0,64)
  const int f = fh * 64 + fl;

  // ---- B into registers (L2-resident: 196KB shared by all blocks) ----
  const char* Wb = (const char*)W2;
  s16x8 breg[3][8];
#pragma unroll
  for (int g = 0; g < 3; ++g)
#pragma unroll
    for (int ks = 0; ks < 8; ++ks)
      breg[g][ks] = *(const s16x8*)(Wb + (size_t)(g * 128 + f) * 512 + ks * 64 + kg * 16);
  const float bz0 = bias[f], bz1 = bias[128 + f], bz2 = bias[256 + f];

  // ---- stage A tile: 32KB via global_load_lds, 8 insts/thread-wave ----
  const char* Ab = (const char*)A + (size_t)m0 * 512;
  const int half = lane >> 5;
  const int lin = (lane & 31) * 16;
#pragma unroll
  for (int it = 0; it < 8; ++it) {
    int inst = w4 * 8 + it;
    int row = inst * 2 + half;
    const char* src = Ab + row * 512 + (lin ^ ((row & 7) << 4));
    __builtin_amdgcn_global_load_lds(
        (const __attribute__((address_space(1))) unsigned int*)src,
        (__attribute__((address_space(3))) unsigned int*)(&As[0] + inst * 1024), 16, 0, 0);
  }
  VMCNT(0);                                      // A staged + B regs loaded
  __builtin_amdgcn_s_barrier();

  // ---- MFMA: 96 per wave ----
  f32x4 acc[4][3];
#pragma unroll
  for (int mf = 0; mf < 4; ++mf)
#pragma unroll
    for (int g = 0; g < 3; ++g) acc[mf][g] = (f32x4)(0.f);
  __builtin_amdgcn_s_setprio(1);
#pragma unroll
  for (int ks = 0; ks < 8; ++ks) {
    s16x8 afr[4];
#pragma unroll
    for (int mf = 0; mf < 4; ++mf) {
      int row = mf * 16 + col;
      afr[mf] = *(const s16x8*)(&As[0] + row * 512 + ((ks * 64 + kg * 16) ^ ((row & 7) << 4)));
    }
#pragma unroll
    for (int g = 0; g < 3; ++g)
#pragma unroll
      for (int mf = 0; mf < 4; ++mf)
        acc[mf][g] = __builtin_amdgcn_mfma_f32_16x16x32_bf16(afr[mf], breg[g][ks], acc[mf][g], 0, 0, 0);
  }
  __builtin_amdgcn_s_setprio(0);

  // ---- epilogue: act -> bf16 -> swizzled staging ----
#pragma unroll
  for (int mf = 0; mf < 4; ++mf) {
    int mbase = mf * 16 + kg * 4;
#pragma unroll
    for (int r = 0; r < 4; ++r) {
      int mloc = mbase + r;
      int n = (m0 + mloc) >> lgL;
      float o0 = acc[mf][0][r] + bz0 + CI0[n * 128 + f];
      float o1 = acc[mf][1][r] + bz1 + CI1[n * 128 + f];
      float o2 = acc[mf][2][r] + bz2;
      __hip_bfloat16 h = __float2bfloat16(gated_act(o0, o1, o2));
      *(short*)(&Stg[0] + mloc * 128 + ((fl * 2) ^ ((mloc & 7) << 4))) = *(short*)&h;
    }
  }
  __syncthreads();

  // ---- coalesced store: 64 rows x 128B (this f-half), 2 passes x 256 x 16B ----
#pragma unroll
  for (int p = 0; p < 2; ++p) {
    int idx = p * 256 + tid;
    int row = idx >> 3;
    int off = (idx & 7) * 16;
    s16x8 v = *(const s16x8*)(&Stg[0] + row * 128 + (off ^ ((row & 7) << 4)));
    *(s16x8*)((char*)out + (size_t)(m0 + row) * 256 + fh * 128 + off) = v;
  }
}

// ---- MFMA tail: one layer (RIN input rows/window -> RIN/2), 8 windows/block ----
template <int MF, int RIN>
__device__ __forceinline__ void tail_layer(
    const char* hsrc, char* hdst, const __hip_bfloat16* Wl, const float* bb,
    const float* ciA, const float* ciB, int b, int w4, int lane) {
  const int col = lane & 15, kg = lane >> 4;
  constexpr int ROUT = RIN / 2;
  constexpr int MV = 8 * ROUT;
  f32x4 acc[MF][2][3];
#pragma unroll
  for (int mf = 0; mf < MF; ++mf)
#pragma unroll
    for (int ff = 0; ff < 2; ++ff)
#pragma unroll
      for (int g = 0; g < 3; ++g) acc[mf][ff][g] = (f32x4)(0.f);
  const char* Wb = (const char*)Wl;
#pragma unroll
  for (int ks = 0; ks < 8; ++ks) {
    s16x8 afr[MF];
    int ke = ks * 32 + kg * 8;
    int k2 = ke >> 7, c = ke & 127;
#pragma unroll
    for (int mf = 0; mf < MF; ++mf) {
      int m = mf * 16 + col;
      int mm = m < MV ? m : MV - 1;
      int win = mm / ROUT, jp = mm % ROUT;
      int srow = win * RIN + 2 * jp + k2;
      afr[mf] = *(const s16x8*)(hsrc + srow * 256 + ((c * 2) ^ ((srow & 7) << 4)));
    }
#pragma unroll
    for (int g = 0; g < 3; ++g)
#pragma unroll
      for (int ff = 0; ff < 2; ++ff) {
        int f = w4 * 32 + ff * 16 + col;
        s16x8 bfr = *(const s16x8*)(Wb + (size_t)(g * 128 + f) * 512 + ks * 64 + kg * 16);
#pragma unroll
        for (int mf = 0; mf < MF; ++mf)
          acc[mf][ff][g] = __builtin_amdgcn_mfma_f32_16x16x32_bf16(afr[mf], bfr, acc[mf][ff][g], 0, 0, 0);
      }
  }
#pragma unroll
  for (int mf = 0; mf < MF; ++mf)
#pragma unroll
    for (int ff = 0; ff < 2; ++ff) {
      int f = w4 * 32 + ff * 16 + col;
      float b0 = bb[f], b1 = bb[128 + f], b2 = bb[256 + f];
#pragma unroll
      for (int r = 0; r < 4; ++r) {
        int m = mf * 16 + kg * 4 + r;
        if (m < MV) {
          int win = m / ROUT;
          int n = b * 8 + win;
          float o0 = acc[mf][ff][0][r] + b0 + ciA[n * 128 + f];
          float o1 = acc[mf][ff][1][r] + b1 + ciB[n * 128 + f];
          float o2 = acc[mf][ff][2][r] + b2;
          __hip_bfloat16 h = __float2bfloat16(gated_act(o0, o1, o2));
          *(short*)(hdst + m * 256 + ((f * 2) ^ ((m & 7) << 4))) = *(short*)&h;
        }
      }
    }
}

// fused tail: layers 6,7,8 + head. 8 windows/block, 100 blocks, 256 threads.
__global__ __launch_bounds__(256) void k_tail(
    const __hip_bfloat16* __restrict__ H8,
    const __hip_bfloat16* __restrict__ W2b,
    const float* __restrict__ cb,
    const float* __restrict__ CIb,
    const __hip_bfloat16* __restrict__ PWb,
    const float* __restrict__ pb_,
    const float* __restrict__ mw_, const float* __restrict__ mb_,
    const float* __restrict__ sw_, const float* __restrict__ sb_,
    const float* __restrict__ eps_, const float* __restrict__ signal,
    float* __restrict__ prev_next, float* __restrict__ out_mean,
    float* __restrict__ out_logvar, float* __restrict__ out_tails) {
  __shared__ char hA[64 * 256];
  __shared__ char hB[32 * 256];
  __shared__ float psm[8][256];
  __shared__ float psv[8][256];
  const int b = blockIdx.x;
  const int tid = threadIdx.x;
  const int lane = tid & 63, w4 = tid >> 6;
  const int col = lane & 15, kg = lane >> 4;

  {
    const char* src = (const char*)(H8 + (size_t)b * 64 * 128);
#pragma unroll
    for (int p = 0; p < 4; ++p) {
      int idx = p * 256 + tid;
      int row = idx >> 4;
      int off = (idx & 15) * 16;
      s16x8 v = *(const s16x8*)(src + row * 256 + off);
      *(s16x8*)(hA + row * 256 + (off ^ ((row & 7) << 4))) = v;
    }
  }
  __syncthreads();

  tail_layer<2, 8>(hA, hB, W2b + (size_t)5 * 384 * 256, cb + (size_t)5 * 384,
                   CIb + (size_t)(6 * 2 + 0) * NWIN * F, CIb + (size_t)(6 * 2 + 1) * NWIN * F,
                   b, w4, lane);
  __syncthreads();
  tail_layer<1, 4>(hB, hA, W2b + (size_t)6 * 384 * 256, cb + (size_t)6 * 384,
                   CIb + (size_t)(7 * 2 + 0) * NWIN * F, CIb + (size_t)(7 * 2 + 1) * NWIN * F,
                   b, w4, lane);
  __syncthreads();
  tail_layer<1, 2>(hA, hB, W2b + (size_t)7 * 384 * 256, cb + (size_t)7 * 384,
                   CIb + (size_t)(8 * 2 + 0) * NWIN * F, CIb + (size_t)(8 * 2 + 1) * NWIN * F,
                   b, w4, lane);
  __syncthreads();

  {
    f32x4 acc2[4];
#pragma unroll
    for (int nf = 0; nf < 4; ++nf) acc2[nf] = (f32x4)(0.f);
    const char* PB = (const char*)PWb;
#pragma unroll
    for (int ks = 0; ks < 4; ++ks) {
      int ke = ks * 32 + kg * 8;
      int m = col;
      int win = m < 8 ? m : 7;
      s16x8 afr = *(const s16x8*)(hB + win * 256 + ((ke * 2) ^ ((win & 7) << 4)));
#pragma unroll
      for (int nf = 0; nf < 4; ++nf) {
        int o = w4 * 64 + nf * 16 + col;
        s16x8 bfr = *(const s16x8*)(PB + (size_t)o * 256 + ks * 64 + kg * 16);
        acc2[nf] = __builtin_amdgcn_mfma_f32_16x16x32_bf16(afr, bfr, acc2[nf], 0, 0, 0);
      }
    }
#pragma unroll
    for (int nf = 0; nf < 4; ++nf) {
      int o = w4 * 64 + nf * 16 + col;
      float pb = pb_[o], mw = mw_[o], sw = sw_[o];
#pragma unroll
      for (int r = 0; r < 4; ++r) {
        int m = kg * 4 + r;
        if (m < 8) {
          float p = fmaxf(acc2[nf][r] + pb, 0.f);
          psm[m][o] = p * mw;
          psv[m][o] = p * sw;
        }
      }
    }
  }
  __syncthreads();

  {
    int win = tid >> 5, l32 = tid & 31;
    const float* pm = &psm[win][l32 * 8];
    const float* pv = &psv[win][l32 * 8];
    float sm = 0.f, sv = 0.f;
#pragma unroll
    for (int e = 0; e < 8; ++e) { sm += pm[e]; sv += pv[e]; }
#pragma unroll
    for (int off = 16; off > 0; off >>= 1) {
      sm += __shfl_down(sm, off, 32);
      sv += __shfl_down(sv, off, 32);
    }
    if (l32 == 0) {
      int n = b * 8 + win;
      float mean = sm + mb_[0];
      float logv = sv + sb_[0];
      float nx = eps_[n] * expf(0.5f * logv) + mean;
      if (prev_next) prev_next[RFS + n] = nx;
      if (out_mean) { out_mean[n] = mean; out_logvar[n] = logv; }
      if (n >= NWIN - RFS) out_tails[n - (NWIN - RFS)] = nx;
    }
  }
  if (prev_next && tid < 8 && (b * 8 + tid) < RFS)
    prev_next[b * 8 + tid] = signal[b * 8 + tid];
}

// ---------------- host ----------------

extern "C" void kernel_launch(void* const* d_in, const int* in_sizes, int n_in,
                              void* d_out, int out_size, void* d_ws, size_t ws_size,
                              hipStream_t stream) {
  const float* mgc      = (const float*)d_in[0];
  const float* signal   = (const float*)d_in[1];
  const float* cond_w   = (const float*)d_in[2];
  const float* cond_b   = (const float*)d_in[3];
  const float* conv0_w  = (const float*)d_in[4];
  const float* conv0_b  = (const float*)d_in[5];
  const float* convL_w  = (const float*)d_in[6];
  const float* convL_b  = (const float*)d_in[7];
  const float* condlin_w= (const float*)d_in[8];
  const float* condlin_b= (const float*)d_in[9];
  const float* pre_w    = (const float*)d_in[10];
  const float* pre_b    = (const float*)d_in[11];
  const float* mean_w   = (const float*)d_in[12];
  const float* mean_b   = (const float*)d_in[13];
  const float* std_w    = (const float*)d_in[14];
  const float* std_b    = (const float*)d_in[15];
  const float* eps      = (const float*)d_in[16];
  float* out = (float*)d_out;

  float* wsf   = (float*)d_ws;
  float* cond  = wsf;
  float* CI    = cond + 48000;
  float* prevb = CI + 7372800;
  float* CV    = prevb + 5248;
  float* base  = CV + 503040;
  __hip_bfloat16* W2   = (__hip_bfloat16*)base;
  __hip_bfloat16* PW   = W2 + 3145728;
  __hip_bfloat16* bufA = PW + 131072;
  __hip_bfloat16* bufB = bufA + 26214400 + 65536;

  k_cond<<<(NWIN * MGCS + 255) / 256, 256, 0, stream>>>(mgc, cond_w, cond_b, cond);
  k_ci<<<dim3(72, 7), 256, 0, stream>>>(cond, condlin_w, condlin_b, CI);
  k_wt<<<(NBLK * 8 * 384 * 256 + 255) / 256, 256, 0, stream>>>(convL_w, W2);
  k_wt2<<<(NBLK * 256 * 128 + 255) / 256, 256, 0, stream>>>(pre_w, PW);
  k_outsig<<<(NWIN + 255) / 256, 256, 0, stream>>>(signal, out);

  for (int blk = 0; blk < NBLK; ++blk) {
    const float* prev = (blk == 0) ? signal : (prevb + (size_t)(blk - 1) * 1312);
    const float* CIb = CI + (size_t)(blk * NLAY) * 2 * NWIN * F;
    k_pre0<<<(1310 * 384 + 255) / 256, 256, 0, stream>>>(
        prev, conv0_w + (size_t)blk * 3 * F * 2, conv0_b + (size_t)blk * 3 * F, CV);
    k_layer0<<<(NWIN * 256 * 16 + 255) / 256, 256, 0, stream>>>(CV, CIb, bufA);

    __hip_bfloat16* cur = bufA;
    __hip_bfloat16* nxt = bufB;
    for (int l = 1; l <= 5; ++l) {
      int Lout = 256 >> l;
      int M = NWIN * Lout;
      const float* ci0 = CI + ((size_t)((blk * NLAY + l) * 2 + 0)) * NWIN * F;
      const float* ci1 = CI + ((size_t)((blk * NLAY + l) * 2 + 1)) * NWIN * F;
      const __hip_bfloat16* wt = W2 + (size_t)(blk * 8 + (l - 1)) * 384 * 256;
      const float* bs = convL_b + (size_t)((blk * 8 + (l - 1)) * 3) * F;
      int ntiles = M / 64;
      k_gemm2<<<dim3(2, ntiles), 256, 0, stream>>>(cur, wt, bs, ci0, ci1, nxt, M, 8 - l);
      __hip_bfloat16* tmp = cur; cur = nxt; nxt = tmp;
    }
    k_tail<<<100, 256, 0, stream>>>(
        cur, W2 + (size_t)blk * 8 * 384 * 256,
        convL_b + (size_t)blk * 8 * 3 * F, CIb,
        PW + (size_t)blk * 256 * 128, pre_b + (size_t)blk * 256,
        mean_w + (size_t)blk * 256, mean_b + blk,
        std_w + (size_t)blk * 256, std_b + blk,
        eps + (size_t)blk * NWIN, signal,
        (blk < 3) ? (prevb + (size_t)blk * 1312) : nullptr,
        (blk == 3) ? (out + 800) : nullptr,
        (blk == 3) ? (out + 1600) : nullptr,
        out + 2400 + (size_t)blk * 512);
  }
}

// Round 10
// 677.923 us; speedup vs baseline: 1.4263x; 1.1303x over previous
//
#include <hip/hip_runtime.h>
#include <hip/hip_bf16.h>

#define F 128
#define MGCS 60
#define NWIN 800
#define RFS 512
#define NBLK 4
#define NLAY 9
#define SQF 0.70710678118f

typedef __attribute__((ext_vector_type(8))) short s16x8;
typedef __attribute__((ext_vector_type(4))) float f32x4;

#define VMCNT(n) asm volatile("s_waitcnt vmcnt(" #n ")" ::: "memory")

__device__ __forceinline__ float gated_act(float o0, float o1, float o2) {
  o0 = fminf(fmaxf(o0, -21.f), 21.f);
  o1 = fminf(fmaxf(o1, -21.f), 21.f);
  float a = __expf(2.f * o0);
  float b = __expf(-o1);
  float r = (a - 1.f) * __builtin_amdgcn_rcpf((a + 1.f) * (1.f + b));
  return (r + o2) * SQF;
}

// ---------------- precompute kernels ----------------

__global__ void k_cond(const float* __restrict__ mgc, const float* __restrict__ cond_w,
                       const float* __restrict__ cond_b, float* __restrict__ cond) {
  int i = blockIdx.x * blockDim.x + threadIdx.x;
  if (i >= NWIN * MGCS) return;
  int n = i / MGCS, m = i % MGCS;
  int t = n / 200, u = n % 200;
  const float* wrow = cond_w + (size_t)(u * MGCS + m) * MGCS;
  const float* mr = mgc + t * MGCS;
  float s = cond_b[u * MGCS + m];
#pragma unroll
  for (int k = 0; k < MGCS; ++k) s += mr[k] * wrow[k];
  cond[i] = tanhf(s);
}

__global__ __launch_bounds__(256) void k_ci(
    const float* __restrict__ cond, const float* __restrict__ clw,
    const float* __restrict__ clb, float* __restrict__ CI) {
  int w = blockIdx.x;
  int n0 = blockIdx.y * 128;
  __shared__ float wsh[128][61];
  __shared__ float csh[128][61];
  int tid = threadIdx.x;
  for (int idx = tid; idx < 128 * MGCS; idx += 256) {
    int f = idx / MGCS, k = idx % MGCS;
    wsh[f][k] = clw[((size_t)w * 128 + f) * MGCS + k];
  }
  for (int idx = tid; idx < 128 * MGCS; idx += 256) {
    int n = idx / MGCS, k = idx % MGCS;
    csh[n][k] = (n0 + n < NWIN) ? cond[(n0 + n) * MGCS + k] : 0.f;
  }
  __syncthreads();
  int tn = tid >> 4, tf = tid & 15;
  float acc[8][8] = {};
  for (int k = 0; k < MGCS; ++k) {
    float a[8], b[8];
#pragma unroll
    for (int i = 0; i < 8; ++i) a[i] = csh[i * 16 + tn][k];
#pragma unroll
    for (int j = 0; j < 8; ++j) b[j] = wsh[j * 16 + tf][k];
#pragma unroll
    for (int i = 0; i < 8; ++i)
#pragma unroll
      for (int j = 0; j < 8; ++j) acc[i][j] += a[i] * b[j];
  }
  float bb[8];
#pragma unroll
  for (int j = 0; j < 8; ++j) bb[j] = clb[w * 128 + j * 16 + tf];
#pragma unroll
  for (int i = 0; i < 8; ++i) {
    int n = n0 + i * 16 + tn;
    if (n < NWIN) {
#pragma unroll
      for (int j = 0; j < 8; ++j)
        CI[((size_t)w * NWIN + n) * 128 + j * 16 + tf] = acc[i][j] + bb[j];
    }
  }
}

__global__ void k_wt(const float* __restrict__ convL_w, __hip_bfloat16* __restrict__ W2) {
  int i = blockIdx.x * blockDim.x + threadIdx.x;
  const int total = NBLK * 8 * 384 * 256;
  if (i >= total) return;
  int k = i & 255;
  int tf = (i >> 8) % 384;
  int wl = i / (384 * 256);
  int t = tf >> 7, f = tf & 127;
  int k2 = k >> 7, c = k & 127;
  W2[i] = __float2bfloat16(convL_w[(((size_t)(wl * 3 + t) * 128 + f) * 128 + c) * 2 + k2]);
}

__global__ void k_wt2(const float* __restrict__ pre_w, __hip_bfloat16* __restrict__ PW) {
  int i = blockIdx.x * blockDim.x + threadIdx.x;
  if (i < NBLK * 256 * 128) PW[i] = __float2bfloat16(pre_w[i]);
}

__global__ void k_outsig(const float* __restrict__ signal, float* __restrict__ out) {
  int i = blockIdx.x * blockDim.x + threadIdx.x;
  if (i < NWIN) out[i] = signal[RFS + i];
}

// ---------------- per-block kernels ----------------

__global__ void k_pre0(const float* __restrict__ prev, const float* __restrict__ w0,
                       const float* __restrict__ b0, float* __restrict__ CV) {
  int i = blockIdx.x * blockDim.x + threadIdx.x;
  if (i >= 1310 * 384) return;
  int tf = i % 384, s = i / 384;
  CV[i] = b0[tf] + prev[s] * w0[tf * 2] + prev[s + 1] * w0[tf * 2 + 1];
}

__global__ void k_layer0(const float* __restrict__ CV, const float* __restrict__ CIb,
                         __hip_bfloat16* __restrict__ out) {
  int i = blockIdx.x * blockDim.x + threadIdx.x;
  if (i >= NWIN * 256 * 16) return;
  int fg = i & 15;
  int rest = i >> 4;
  int j = rest & 255;
  int n = rest >> 8;
  int f0 = fg * 8;
  const float* cv = CV + (size_t)(n + 2 * j) * 384;
  const float* ci = CIb + (size_t)n * F;
  float4 c0a = *(const float4*)(cv + f0),       c0b = *(const float4*)(cv + f0 + 4);
  float4 c1a = *(const float4*)(cv + 128 + f0), c1b = *(const float4*)(cv + 132 + f0);
  float4 c2a = *(const float4*)(cv + 256 + f0), c2b = *(const float4*)(cv + 260 + f0);
  float4 i0a = *(const float4*)(ci + f0),       i0b = *(const float4*)(ci + f0 + 4);
  float4 i1a = *(const float4*)(ci + (size_t)NWIN * F + f0);
  float4 i1b = *(const float4*)(ci + (size_t)NWIN * F + f0 + 4);
  s16x8 res;
#pragma unroll
  for (int e = 0; e < 8; ++e) {
    float o0 = ((e < 4) ? (&c0a.x)[e] : (&c0b.x)[e - 4]) + ((e < 4) ? (&i0a.x)[e] : (&i0b.x)[e - 4]);
    float o1 = ((e < 4) ? (&c1a.x)[e] : (&c1b.x)[e - 4]) + ((e < 4) ? (&i1a.x)[e] : (&i1b.x)[e - 4]);
    float o2 = (e < 4) ? (&c2a.x)[e] : (&c2b.x)[e - 4];
    __hip_bfloat16 h = __float2bfloat16(gated_act(o0, o1, o2));
    res[e] = *(short*)&h;
  }
  *(s16x8*)(out + ((size_t)(n * 256 + j)) * F + f0) = res;
}

// ---- fused layer slice: GEMM rows [mbase..mbase+16*MFR) x (FF*16 f-cols, 3 gates)
// src: LDS [*][512B] (XOR swz). dst: PAIR -> [*][512B] pair-packed; FLAT -> [*][256B].
template <int MFR, int FF, bool FLAT>
__device__ __forceinline__ void fuse_layer(
    const char* src, char* dst, const char* Wb, const float* __restrict__ bb,
    const float* __restrict__ ciA, const float* __restrict__ ciB,
    int n0, int logLW, int MV, int mbase, int fbase, int lane) {
  const int col = lane & 15, kg = lane >> 4;
  f32x4 acc[MFR][FF][3];
#pragma unroll
  for (int mf = 0; mf < MFR; ++mf)
#pragma unroll
    for (int ff = 0; ff < FF; ++ff)
#pragma unroll
      for (int g = 0; g < 3; ++g) acc[mf][ff][g] = (f32x4)(0.f);
#pragma unroll
  for (int ks = 0; ks < 8; ++ks) {
    s16x8 breg[FF][3];
#pragma unroll
    for (int ff = 0; ff < FF; ++ff)
#pragma unroll
      for (int g = 0; g < 3; ++g) {
        int tf = g * 128 + fbase + ff * 16 + col;
        breg[ff][g] = *(const s16x8*)(Wb + (size_t)tf * 512 + ks * 64 + kg * 16);
      }
    s16x8 afr[MFR];
#pragma unroll
    for (int mf = 0; mf < MFR; ++mf) {
      int row = mbase + mf * 16 + col;
      row = row < MV ? row : MV - 1;
      afr[mf] = *(const s16x8*)(src + row * 512 + ((ks * 64 + kg * 16) ^ ((row & 7) << 4)));
    }
#pragma unroll
    for (int ff = 0; ff < FF; ++ff)
#pragma unroll
      for (int g = 0; g < 3; ++g)
#pragma unroll
        for (int mf = 0; mf < MFR; ++mf)
          acc[mf][ff][g] = __builtin_amdgcn_mfma_f32_16x16x32_bf16(afr[mf], breg[ff][g], acc[mf][ff][g], 0, 0, 0);
  }
#pragma unroll
  for (int mf = 0; mf < MFR; ++mf)
#pragma unroll
    for (int ff = 0; ff < FF; ++ff) {
      int f = fbase + ff * 16 + col;
      float b0 = bb[f], b1 = bb[128 + f], b2 = bb[256 + f];
#pragma unroll
      for (int r = 0; r < 4; ++r) {
        int orow = mbase + mf * 16 + kg * 4 + r;
        if (orow < MV) {
          int n = n0 + (orow >> logLW);
          float o0 = acc[mf][ff][0][r] + b0 + ciA[n * 128 + f];
          float o1 = acc[mf][ff][1][r] + b1 + ciB[n * 128 + f];
          float o2 = acc[mf][ff][2][r] + b2;
          __hip_bfloat16 h = __float2bfloat16(gated_act(o0, o1, o2));
          if (FLAT) {
            *(short*)(dst + orow * 256 + ((f * 2) ^ ((orow & 7) << 4))) = *(short*)&h;
          } else {
            int trow = ((orow >> logLW) << (logLW - 1)) | ((orow & ((1 << logLW) - 1)) >> 1);
            int kb = ((orow & 1) * 128 + f) * 2;
            *(short*)(dst + trow * 512 + (kb ^ ((trow & 7) << 4))) = *(short*)&h;
          }
        }
      }
    }
}

// fused layers 1-2, one window per block, 8 waves.
__global__ __launch_bounds__(512, 1) void k_fuse12(
    const __hip_bfloat16* __restrict__ A0, const __hip_bfloat16* __restrict__ W2b,
    const float* __restrict__ cb, const float* __restrict__ CIb,
    __hip_bfloat16* __restrict__ outC) {
  __shared__ char Ain[128 * 512];
  __shared__ char Bp[64 * 512];
  const int n = blockIdx.x;
  const int tid = threadIdx.x;
  const int lane = tid & 63, wid = tid >> 6;
  const char* srcg = (const char*)A0 + (size_t)n * 65536;
  const int half = lane >> 5, lin = (lane & 31) * 16;
#pragma unroll
  for (int it = 0; it < 8; ++it) {
    int inst = wid * 8 + it;
    int row = inst * 2 + half;
    __builtin_amdgcn_global_load_lds(
        (const __attribute__((address_space(1))) unsigned int*)(srcg + row * 512 + (lin ^ ((row & 7) << 4))),
        (__attribute__((address_space(3))) unsigned int*)(Ain + inst * 1024), 16, 0, 0);
  }
  VMCNT(0);
  __syncthreads();
  const int fbase = wid * 16;
  const char* W0 = (const char*)W2b;
  const char* W1 = (const char*)W2b + (size_t)384 * 512;
  const float* c1A = CIb + (size_t)(1 * 2 + 0) * NWIN * F;
  const float* c1B = CIb + (size_t)(1 * 2 + 1) * NWIN * F;
  const float* c2A = CIb + (size_t)(2 * 2 + 0) * NWIN * F;
  const float* c2B = CIb + (size_t)(2 * 2 + 1) * NWIN * F;
  fuse_layer<4, 1, false>(Ain, Bp, W0, cb, c1A, c1B, n, 7, 128, 0, fbase, lane);
  fuse_layer<4, 1, false>(Ain, Bp, W0, cb, c1A, c1B, n, 7, 128, 64, fbase, lane);
  __syncthreads();
  fuse_layer<4, 1, true>(Bp, Ain, W1, cb + 384, c2A, c2B, n, 6, 64, 0, fbase, lane);
  __syncthreads();
  // coalesced store of l=2 output: 64 rows x 256B
#pragma unroll
  for (int p = 0; p < 2; ++p) {
    int idx = p * 512 + tid;
    int row = idx >> 4;
    int off = (idx & 15) * 16;
    s16x8 v = *(const s16x8*)(Ain + row * 256 + (off ^ ((row & 7) << 4)));
    *(s16x8*)((char*)outC + (size_t)n * 16384 + row * 256 + off) = v;
  }
}

// fused layers 3-8 + head, 4 windows per block, 4 waves.
__global__ __launch_bounds__(256, 1) void k_tail6(
    const __hip_bfloat16* __restrict__ C2, const __hip_bfloat16* __restrict__ W2b,
    const float* __restrict__ cb, const float* __restrict__ CIb,
    const __hip_bfloat16* __restrict__ PWb, const float* __restrict__ pb_,
    const float* __restrict__ mw_, const float* __restrict__ mb_,
    const float* __restrict__ sw_, const float* __restrict__ sb_,
    const float* __restrict__ eps_, const float* __restrict__ signal,
    float* __restrict__ prev_next, float* __restrict__ out_mean,
    float* __restrict__ out_logvar, float* __restrict__ out_tails) {
  __shared__ char Ain[128 * 512];
  __shared__ char Bp[64 * 512];
  __shared__ float psm[4][256];
  __shared__ float psv[4][256];
  const int b = blockIdx.x, n0 = b * 4;
  const int tid = threadIdx.x;
  const int lane = tid & 63, wid = tid >> 6;
  const int col = lane & 15, kg = lane >> 4;
  const char* srcg = (const char*)C2 + (size_t)n0 * 16384;
  const int half = lane >> 5, lin = (lane & 31) * 16;
#pragma unroll
  for (int it = 0; it < 16; ++it) {
    int inst = wid * 16 + it;
    int row = inst * 2 + half;
    __builtin_amdgcn_global_load_lds(
        (const __attribute__((address_space(1))) unsigned int*)(srcg + row * 512 + (lin ^ ((row & 7) << 4))),
        (__attribute__((address_space(3))) unsigned int*)(Ain + inst * 1024), 16, 0, 0);
  }
  VMCNT(0);
  __syncthreads();
  const int fbase = wid * 32;
#define WLp(lm) ((const char*)W2b + (size_t)(lm) * 384 * 512)
#define CIL(l, t) (CIb + (size_t)((l) * 2 + (t)) * NWIN * F)
  fuse_layer<4, 2, false>(Ain, Bp, WLp(2), cb + 2 * 384, CIL(3, 0), CIL(3, 1), n0, 5, 128, 0, fbase, lane);
  fuse_layer<4, 2, false>(Ain, Bp, WLp(2), cb + 2 * 384, CIL(3, 0), CIL(3, 1), n0, 5, 128, 64, fbase, lane);
  __syncthreads();
  fuse_layer<4, 2, false>(Bp, Ain, WLp(3), cb + 3 * 384, CIL(4, 0), CIL(4, 1), n0, 4, 64, 0, fbase, lane);
  __syncthreads();
  fuse_layer<2, 2, false>(Ain, Bp, WLp(4), cb + 4 * 384, CIL(5, 0), CIL(5, 1), n0, 3, 32, 0, fbase, lane);
  __syncthreads();
  fuse_layer<1, 2, false>(Bp, Ain, WLp(5), cb + 5 * 384, CIL(6, 0), CIL(6, 1), n0, 2, 16, 0, fbase, lane);
  __syncthreads();
  fuse_layer<1, 2, false>(Ain, Bp, WLp(6), cb + 6 * 384, CIL(7, 0), CIL(7, 1), n0, 1, 8, 0, fbase, lane);
  __syncthreads();
  fuse_layer<1, 2, true>(Bp, Ain, WLp(7), cb + 7 * 384, CIL(8, 0), CIL(8, 1), n0, 0, 4, 0, fbase, lane);
  __syncthreads();

  // head: [4 rows pad 16][K=128] x PW[256][128]^T
  {
    f32x4 acc2[4];
#pragma unroll
    for (int nf = 0; nf < 4; ++nf) acc2[nf] = (f32x4)(0.f);
    const char* PB = (const char*)PWb;
    int row = col < 4 ? col : 3;
#pragma unroll
    for (int ks = 0; ks < 4; ++ks) {
      s16x8 afr = *(const s16x8*)(Ain + row * 256 + ((ks * 64 + kg * 16) ^ ((row & 7) << 4)));
#pragma unroll
      for (int nf = 0; nf < 4; ++nf) {
        int o = wid * 64 + nf * 16 + col;
        s16x8 bfr = *(const s16x8*)(PB + (size_t)o * 256 + ks * 64 + kg * 16);
        acc2[nf] = __builtin_amdgcn_mfma_f32_16x16x32_bf16(afr, bfr, acc2[nf], 0, 0, 0);
      }
    }
#pragma unroll
    for (int nf = 0; nf < 4; ++nf) {
      int o = wid * 64 + nf * 16 + col;
      float pb = pb_[o], mw = mw_[o], sw = sw_[o];
#pragma unroll
      for (int r = 0; r < 4; ++r) {
        int m = kg * 4 + r;
        if (m < 4) {
          float p = fmaxf(acc2[nf][r] + pb, 0.f);
          psm[m][o] = p * mw;
          psv[m][o] = p * sw;
        }
      }
    }
  }
  __syncthreads();
  // reduce: wave w handles window w (lane sums 4 o's, then shfl)
  {
    float sm = 0.f, sv = 0.f;
#pragma unroll
    for (int e = 0; e < 4; ++e) {
      sm += psm[wid][lane * 4 + e];
      sv += psv[wid][lane * 4 + e];
    }
#pragma unroll
    for (int off = 32; off > 0; off >>= 1) {
      sm += __shfl_down(sm, off);
      sv += __shfl_down(sv, off);
    }
    if (lane == 0) {
      int nn = n0 + wid;
      float mean = sm + mb_[0];
      float logv = sv + sb_[0];
      float nx = eps_[nn] * expf(0.5f * logv) + mean;
      if (prev_next) prev_next[RFS + nn] = nx;
      if (out_mean) { out_mean[nn] = mean; out_logvar[nn] = logv; }
      if (nn >= NWIN - RFS) out_tails[nn - (NWIN - RFS)] = nx;
    }
  }
  if (prev_next && tid < 4 && n0 + tid < RFS)
    prev_next[n0 + tid] = signal[n0 + tid];
}

// ---------------- host ----------------

extern "C" void kernel_launch(void* const* d_in, const int* in_sizes, int n_in,
                              void* d_out, int out_size, void* d_ws, size_t ws_size,
                              hipStream_t stream) {
  const float* mgc      = (const float*)d_in[0];
  const float* signal   = (const float*)d_in[1];
  const float* cond_w   = (const float*)d_in[2];
  const float* cond_b   = (const float*)d_in[3];
  const float* conv0_w  = (const float*)d_in[4];
  const float* conv0_b  = (const float*)d_in[5];
  const float* convL_w  = (const float*)d_in[6];
  const float* convL_b  = (const float*)d_in[7];
  const float* condlin_w= (const float*)d_in[8];
  const float* condlin_b= (const float*)d_in[9];
  const float* pre_w    = (const float*)d_in[10];
  const float* pre_b    = (const float*)d_in[11];
  const float* mean_w   = (const float*)d_in[12];
  const float* mean_b   = (const float*)d_in[13];
  const float* std_w    = (const float*)d_in[14];
  const float* std_b    = (const float*)d_in[15];
  const float* eps      = (const float*)d_in[16];
  float* out = (float*)d_out;

  float* wsf   = (float*)d_ws;
  float* cond  = wsf;
  float* CI    = cond + 48000;
  float* prevb = CI + 7372800;
  float* CV    = prevb + 5248;
  float* base  = CV + 503040;
  __hip_bfloat16* W2   = (__hip_bfloat16*)base;     // 3,145,728 bf16
  __hip_bfloat16* PW   = W2 + 3145728;              // 131,072 bf16
  __hip_bfloat16* bufA = PW + 131072;               // l0 out: 26,214,400
  __hip_bfloat16* bufC = bufA + 26214400 + 65536;   // l2 out: 6,553,600

  k_cond<<<(NWIN * MGCS + 255) / 256, 256, 0, stream>>>(mgc, cond_w, cond_b, cond);
  k_ci<<<dim3(72, 7), 256, 0, stream>>>(cond, condlin_w, condlin_b, CI);
  k_wt<<<(NBLK * 8 * 384 * 256 + 255) / 256, 256, 0, stream>>>(convL_w, W2);
  k_wt2<<<(NBLK * 256 * 128 + 255) / 256, 256, 0, stream>>>(pre_w, PW);
  k_outsig<<<(NWIN + 255) / 256, 256, 0, stream>>>(signal, out);

  for (int blk = 0; blk < NBLK; ++blk) {
    const float* prev = (blk == 0) ? signal : (prevb + (size_t)(blk - 1) * 1312);
    const float* CIb = CI + (size_t)(blk * NLAY) * 2 * NWIN * F;
    k_pre0<<<(1310 * 384 + 255) / 256, 256, 0, stream>>>(
        prev, conv0_w + (size_t)blk * 3 * F * 2, conv0_b + (size_t)blk * 3 * F, CV);
    k_layer0<<<(NWIN * 256 * 16 + 255) / 256, 256, 0, stream>>>(CV, CIb, bufA);

    k_fuse12<<<NWIN, 512, 0, stream>>>(
        bufA, W2 + (size_t)blk * 8 * 384 * 256, convL_b + (size_t)blk * 8 * 384, CIb, bufC);

    k_tail6<<<NWIN / 4, 256, 0, stream>>>(
        bufC, W2 + (size_t)blk * 8 * 384 * 256,
        convL_b + (size_t)blk * 8 * 384, CIb,
        PW + (size_t)blk * 256 * 128, pre_b + (size_t)blk * 256,
        mean_w + (size_t)blk * 256, mean_b + blk,
        std_w + (size_t)blk * 256, std_b + blk,
        eps + (size_t)blk * NWIN, signal,
        (blk < 3) ? (prevb + (size_t)blk * 1312) : nullptr,
        (blk == 3) ? (out + 800) : nullptr,
        (blk == 3) ? (out + 1600) : nullptr,
        out + 2400 + (size_t)blk * 512);
  }
}